// Round 1
// baseline (1539.543 us; speedup 1.0000x reference)
//
#include <hip/hip_runtime.h>
#include <hip/hip_bf16.h>
#include <math.h>

#define N_NODES 100000
#define N_EDGES 3200000
#define IN_FEATS 256
#define N_UNITS 32
#define OUT_FEATS 40

// ---------------- degree accumulation ----------------
__global__ void deg_kernel(const int* __restrict__ src, const int* __restrict__ dst,
                           float* __restrict__ outdeg, float* __restrict__ indeg, int E) {
    int i = blockIdx.x * blockDim.x + threadIdx.x;
    if (i < E) {
        atomicAdd(&outdeg[src[i]], 1.0f);
        atomicAdd(&indeg[dst[i]], 1.0f);
    }
}

__global__ void invsqrt_kernel(float* __restrict__ a, float* __restrict__ b, int N) {
    int i = blockIdx.x * blockDim.x + threadIdx.x;
    if (i < N) {
        a[i] = rsqrtf(fmaxf(a[i], 1.0f));
        b[i] = rsqrtf(fmaxf(b[i], 1.0f));
    }
}

// ---------------- layer-1 dense: h[n,32] = (x[n,:] @ W1) * inv_out[n] ----------------
__global__ void gemm1_kernel(const float* __restrict__ x, const float* __restrict__ W1,
                             const float* __restrict__ inv_out, float* __restrict__ h, int N) {
    __shared__ float Ws[IN_FEATS * N_UNITS];  // 32 KB
    for (int idx = threadIdx.x; idx < IN_FEATS * N_UNITS; idx += blockDim.x)
        Ws[idx] = W1[idx];
    __syncthreads();
    int t = blockIdx.x * blockDim.x + threadIdx.x;
    int n = t >> 5;           // node
    int j = t & 31;           // output unit
    if (n >= N) return;
    const float4* xr = (const float4*)(x + (size_t)n * IN_FEATS);
    float s = 0.0f;
    #pragma unroll
    for (int k4 = 0; k4 < IN_FEATS / 4; ++k4) {
        float4 xv = xr[k4];
        int k = k4 * 4;
        s += xv.x * Ws[(k + 0) * N_UNITS + j];
        s += xv.y * Ws[(k + 1) * N_UNITS + j];
        s += xv.z * Ws[(k + 2) * N_UNITS + j];
        s += xv.w * Ws[(k + 3) * N_UNITS + j];
    }
    h[t] = s * inv_out[n];
}

// ---------------- layer-1 edge scatter: agg1[dst,:] += h[src,:] ----------------
__global__ void scatter1_kernel(const float* __restrict__ h, const int* __restrict__ src,
                                const int* __restrict__ dst, float* __restrict__ agg, int E) {
    unsigned t = blockIdx.x * blockDim.x + threadIdx.x;
    if (t >= (unsigned)E * N_UNITS) return;
    unsigned e = t >> 5;
    unsigned j = t & 31;
    int s = src[e];
    int d = dst[e];
    atomicAdd(&agg[(size_t)d * N_UNITS + j], h[(size_t)s * N_UNITS + j]);
}

// ---------------- fused: r = relu(agg1*inv_in + b1)*inv_out ; t2 = r @ W2 ----------------
__global__ void fuse_gemm2_kernel(const float* __restrict__ agg1, const float* __restrict__ inv_in,
                                  const float* __restrict__ inv_out, const float* __restrict__ b1,
                                  const float* __restrict__ W2, float* __restrict__ t2, int N) {
    __shared__ float W2s[N_UNITS * OUT_FEATS];  // 5 KB
    __shared__ float b1s[N_UNITS];
    for (int idx = threadIdx.x; idx < N_UNITS * OUT_FEATS; idx += blockDim.x)
        W2s[idx] = W2[idx];
    if (threadIdx.x < N_UNITS) b1s[threadIdx.x] = b1[threadIdx.x];
    __syncthreads();
    unsigned t = blockIdx.x * blockDim.x + threadIdx.x;
    if (t >= (unsigned)N * OUT_FEATS) return;
    unsigned n = t / OUT_FEATS;
    unsigned o = t % OUT_FEATS;
    float ii = inv_in[n];
    float io = inv_out[n];
    const float* ar = agg1 + (size_t)n * N_UNITS;
    float s = 0.0f;
    #pragma unroll
    for (int k = 0; k < N_UNITS; ++k) {
        float r = fmaxf(fmaf(ar[k], ii, b1s[k]), 0.0f) * io;
        s = fmaf(r, W2s[k * OUT_FEATS + o], s);
    }
    t2[t] = s;
}

// ---------------- layer-2 edge scatter: agg2[dst,:] += t2[src,:] ----------------
__global__ void scatter2_kernel(const float* __restrict__ t2, const int* __restrict__ src,
                                const int* __restrict__ dst, float* __restrict__ agg, int E) {
    unsigned t = blockIdx.x * blockDim.x + threadIdx.x;
    if (t >= (unsigned)E * OUT_FEATS) return;
    unsigned e = t / OUT_FEATS;
    unsigned o = t % OUT_FEATS;
    int s = src[e];
    int d = dst[e];
    atomicAdd(&agg[(size_t)d * OUT_FEATS + o], t2[(size_t)s * OUT_FEATS + o]);
}

// ---------------- finalize: logits = agg2*inv_in + b2 ; out = log_softmax(logits) ----------------
__global__ void finalize_kernel(const float* __restrict__ agg2, const float* __restrict__ inv_in,
                                const float* __restrict__ b2, float* __restrict__ out, int N) {
    int n = blockIdx.x * blockDim.x + threadIdx.x;
    if (n >= N) return;
    float ii = inv_in[n];
    float v[OUT_FEATS];
    float mx = -INFINITY;
    const float* ar = agg2 + (size_t)n * OUT_FEATS;
    #pragma unroll
    for (int o = 0; o < OUT_FEATS; ++o) {
        v[o] = fmaf(ar[o], ii, b2[o]);
        mx = fmaxf(mx, v[o]);
    }
    float sum = 0.0f;
    #pragma unroll
    for (int o = 0; o < OUT_FEATS; ++o) sum += __expf(v[o] - mx);
    float lse = mx + __logf(sum);
    float* orow = out + (size_t)n * OUT_FEATS;
    #pragma unroll
    for (int o = 0; o < OUT_FEATS; ++o) orow[o] = v[o] - lse;
}

extern "C" void kernel_launch(void* const* d_in, const int* in_sizes, int n_in,
                              void* d_out, int out_size, void* d_ws, size_t ws_size,
                              hipStream_t stream) {
    const float* x   = (const float*)d_in[0];
    const float* W1  = (const float*)d_in[1];
    const float* b1  = (const float*)d_in[2];
    const float* W2  = (const float*)d_in[3];
    const float* b2  = (const float*)d_in[4];
    const int*   src = (const int*)d_in[5];
    const int*   dst = (const int*)d_in[6];
    float* out = (float*)d_out;

    // workspace layout (floats)
    float* ws = (float*)d_ws;
    float* inv_out = ws;                         // [N]  (deg accumulated here first)
    float* inv_in  = ws + N_NODES;               // [N]
    float* h       = ws + 2 * N_NODES;           // [N*32]
    float* agg1    = h + (size_t)N_NODES * N_UNITS;        // [N*32]
    float* t2      = agg1 + (size_t)N_NODES * N_UNITS;     // [N*40]
    float* agg2    = t2 + (size_t)N_NODES * OUT_FEATS;     // [N*40]

    // zero the accumulators (ws is poisoned 0xAA before every call)
    hipMemsetAsync(inv_out, 0, 2 * N_NODES * sizeof(float), stream);
    hipMemsetAsync(agg1, 0, (size_t)N_NODES * N_UNITS * sizeof(float), stream);
    hipMemsetAsync(agg2, 0, (size_t)N_NODES * OUT_FEATS * sizeof(float), stream);

    // degrees -> inv sqrt
    deg_kernel<<<(N_EDGES + 255) / 256, 256, 0, stream>>>(src, dst, inv_out, inv_in, N_EDGES);
    invsqrt_kernel<<<(N_NODES + 255) / 256, 256, 0, stream>>>(inv_out, inv_in, N_NODES);

    // layer 1 dense
    gemm1_kernel<<<(N_NODES * N_UNITS + 255) / 256, 256, 0, stream>>>(x, W1, inv_out, h, N_NODES);

    // layer 1 scatter
    {
        unsigned total = (unsigned)N_EDGES * N_UNITS;
        scatter1_kernel<<<(total + 255) / 256, 256, 0, stream>>>(h, src, dst, agg1, N_EDGES);
    }

    // relu + layer 2 dense (fused)
    {
        unsigned total = (unsigned)N_NODES * OUT_FEATS;
        fuse_gemm2_kernel<<<(total + 255) / 256, 256, 0, stream>>>(agg1, inv_in, inv_out, b1, W2, t2, N_NODES);
    }

    // layer 2 scatter
    {
        unsigned total = (unsigned)N_EDGES * OUT_FEATS;
        scatter2_kernel<<<(total + 255) / 256, 256, 0, stream>>>(t2, src, dst, agg2, N_EDGES);
    }

    // bias + log_softmax
    finalize_kernel<<<(N_NODES + 255) / 256, 256, 0, stream>>>(agg2, inv_in, b2, out, N_NODES);
}

// Round 2
// 1009.428 us; speedup vs baseline: 1.5252x; 1.5252x over previous
//
#include <hip/hip_runtime.h>
#include <hip/hip_bf16.h>
#include <math.h>

#define N_NODES 100000
#define N_EDGES 3200000
#define IN_FEATS 256
#define N_UNITS 32
#define OUT_FEATS 40

// ================= degree histograms =================
// outdeg as float (only needed for rsqrt); indeg as int (needed for CSR scan)
__global__ void hist_kernel(const int* __restrict__ src, const int* __restrict__ dst,
                            float* __restrict__ outdegF, int* __restrict__ indegI, int E) {
    int i = blockIdx.x * blockDim.x + threadIdx.x;
    if (i < E) {
        atomicAdd(&outdegF[src[i]], 1.0f);
        atomicAdd(&indegI[dst[i]], 1);
    }
}

__global__ void invsqrt_kernel(float* __restrict__ outdegF, const int* __restrict__ indegI,
                               float* __restrict__ inv_in, int N) {
    int i = blockIdx.x * blockDim.x + threadIdx.x;
    if (i < N) {
        outdegF[i] = rsqrtf(fmaxf(outdegF[i], 1.0f));          // in-place -> inv_out
        inv_in[i]  = rsqrtf(fmaxf((float)indegI[i], 1.0f));
    }
}

// ================= exclusive scan of indeg (3-kernel) =================
__global__ void scan1_kernel(const int* __restrict__ cnt, int* __restrict__ partial,
                             int* __restrict__ bsums, int N) {
    __shared__ int s[256];
    int i = blockIdx.x * 256 + threadIdx.x;
    int v = (i < N) ? cnt[i] : 0;
    s[threadIdx.x] = v;
    __syncthreads();
    for (int off = 1; off < 256; off <<= 1) {
        int t = (threadIdx.x >= off) ? s[threadIdx.x - off] : 0;
        __syncthreads();
        s[threadIdx.x] += t;
        __syncthreads();
    }
    if (i < N) partial[i] = s[threadIdx.x] - v;   // exclusive within block
    if (threadIdx.x == 255) bsums[blockIdx.x] = s[255];
}

__global__ void scan2_kernel(int* __restrict__ bsums, int* __restrict__ bscan, int nb) {
    __shared__ int s[512];
    int v = (threadIdx.x < nb) ? bsums[threadIdx.x] : 0;
    s[threadIdx.x] = v;
    __syncthreads();
    for (int off = 1; off < 512; off <<= 1) {
        int t = (threadIdx.x >= off) ? s[threadIdx.x - off] : 0;
        __syncthreads();
        s[threadIdx.x] += t;
        __syncthreads();
    }
    bscan[threadIdx.x] = s[threadIdx.x] - v;      // exclusive block offsets
}

__global__ void scan3_kernel(const int* __restrict__ partial, const int* __restrict__ bscan,
                             int* __restrict__ offs, int* __restrict__ cursor, int N) {
    int i = blockIdx.x * 256 + threadIdx.x;
    if (i < N) {
        int o = partial[i] + bscan[blockIdx.x];
        offs[i] = o;
        cursor[i] = o;
    }
}

// ================= CSR fill: group edge sources by dst =================
__global__ void fill_csr_kernel(const int* __restrict__ src, const int* __restrict__ dst,
                                int* __restrict__ cursor, int* __restrict__ csr_src, int E) {
    int e = blockIdx.x * blockDim.x + threadIdx.x;
    if (e < E) {
        int d = dst[e];
        int pos = atomicAdd(&cursor[d], 1);
        csr_src[pos] = src[e];
    }
}

// ================= layer-1 dense: h[n,32] = (x[n,:] @ W1) * inv_out[n] =================
// thread = (node, quarter): 4 threads/node, 8 outputs each. W1 broadcast from LDS.
__global__ void __launch_bounds__(256) gemm1_kernel(
        const float* __restrict__ x, const float* __restrict__ W1,
        const float* __restrict__ inv_out, float* __restrict__ h, int N) {
    __shared__ float Ws[IN_FEATS * N_UNITS];  // 32 KB
    for (int idx = threadIdx.x; idx < IN_FEATS * N_UNITS; idx += 256)
        Ws[idx] = W1[idx];
    __syncthreads();
    unsigned t = blockIdx.x * 256 + threadIdx.x;
    unsigned n = t >> 2;
    if (n >= (unsigned)N) return;
    unsigned j0 = (t & 3) * 8;
    float acc[8] = {0, 0, 0, 0, 0, 0, 0, 0};
    const float4* xr = (const float4*)(x + (size_t)n * IN_FEATS);
    #pragma unroll 4
    for (int k4 = 0; k4 < IN_FEATS / 4; ++k4) {
        float4 xv = xr[k4];
        const float* wk = Ws + (k4 * 4) * N_UNITS + j0;
        #pragma unroll
        for (int jj = 0; jj < 8; ++jj) acc[jj] = fmaf(xv.x, wk[jj], acc[jj]);
        #pragma unroll
        for (int jj = 0; jj < 8; ++jj) acc[jj] = fmaf(xv.y, wk[N_UNITS + jj], acc[jj]);
        #pragma unroll
        for (int jj = 0; jj < 8; ++jj) acc[jj] = fmaf(xv.z, wk[2 * N_UNITS + jj], acc[jj]);
        #pragma unroll
        for (int jj = 0; jj < 8; ++jj) acc[jj] = fmaf(xv.w, wk[3 * N_UNITS + jj], acc[jj]);
    }
    float io = inv_out[n];
    float* hr = h + (size_t)n * N_UNITS + j0;
    #pragma unroll
    for (int jj = 0; jj < 8; ++jj) hr[jj] = acc[jj] * io;
}

// ================= layer-1 gather: agg1[n,:] = sum_{e: dst=n} h[csr_src[e],:] =================
// 32 lanes per node, 8 nodes per 256-block; register accumulation, streaming write.
__global__ void gather1_kernel(const float* __restrict__ h, const int* __restrict__ offs,
                               const int* __restrict__ csr_src, float* __restrict__ agg, int N) {
    unsigned tid = threadIdx.x;
    unsigned n = blockIdx.x * 8 + (tid >> 5);
    unsigned j = tid & 31;
    if (n >= (unsigned)N) return;
    int beg = offs[n];
    int end = (n == (unsigned)N - 1) ? N_EDGES : offs[n + 1];
    float a0 = 0.0f, a1 = 0.0f;
    int e = beg;
    for (; e + 1 < end; e += 2) {
        int s0 = csr_src[e];
        int s1 = csr_src[e + 1];
        a0 += h[(size_t)s0 * N_UNITS + j];
        a1 += h[(size_t)s1 * N_UNITS + j];
    }
    if (e < end) a0 += h[(size_t)csr_src[e] * N_UNITS + j];
    agg[(size_t)n * N_UNITS + j] = a0 + a1;
}

// ================= fused: r = relu(agg1*inv_in + b1)*inv_out ; t2 = r @ W2 =================
__global__ void fuse_gemm2_kernel(const float* __restrict__ agg1, const float* __restrict__ inv_in,
                                  const float* __restrict__ inv_out, const float* __restrict__ b1,
                                  const float* __restrict__ W2, float* __restrict__ t2, int N) {
    __shared__ float W2s[N_UNITS * OUT_FEATS];  // 5 KB
    __shared__ float b1s[N_UNITS];
    for (int idx = threadIdx.x; idx < N_UNITS * OUT_FEATS; idx += blockDim.x)
        W2s[idx] = W2[idx];
    if (threadIdx.x < N_UNITS) b1s[threadIdx.x] = b1[threadIdx.x];
    __syncthreads();
    unsigned t = blockIdx.x * blockDim.x + threadIdx.x;
    if (t >= (unsigned)N * OUT_FEATS) return;
    unsigned n = t / OUT_FEATS;
    unsigned o = t % OUT_FEATS;
    float ii = inv_in[n];
    float io = inv_out[n];
    const float* ar = agg1 + (size_t)n * N_UNITS;
    float s = 0.0f;
    #pragma unroll
    for (int k = 0; k < N_UNITS; ++k) {
        float r = fmaxf(fmaf(ar[k], ii, b1s[k]), 0.0f) * io;
        s = fmaf(r, W2s[k * OUT_FEATS + o], s);
    }
    t2[t] = s;
}

// ================= layer-2 gather: agg2[n,:] = sum_{e: dst=n} t2[csr_src[e],:] =================
// 40 lanes per node, 8 nodes per 320-block.
__global__ void gather2_kernel(const float* __restrict__ t2, const int* __restrict__ offs,
                               const int* __restrict__ csr_src, float* __restrict__ agg, int N) {
    unsigned tid = threadIdx.x;
    unsigned n = blockIdx.x * 8 + tid / OUT_FEATS;
    unsigned j = tid % OUT_FEATS;
    if (n >= (unsigned)N) return;
    int beg = offs[n];
    int end = (n == (unsigned)N - 1) ? N_EDGES : offs[n + 1];
    float a0 = 0.0f, a1 = 0.0f;
    int e = beg;
    for (; e + 1 < end; e += 2) {
        int s0 = csr_src[e];
        int s1 = csr_src[e + 1];
        a0 += t2[(size_t)s0 * OUT_FEATS + j];
        a1 += t2[(size_t)s1 * OUT_FEATS + j];
    }
    if (e < end) a0 += t2[(size_t)csr_src[e] * OUT_FEATS + j];
    agg[(size_t)n * OUT_FEATS + j] = a0 + a1;
}

// ================= finalize: logits = agg2*inv_in + b2 ; out = log_softmax =================
__global__ void finalize_kernel(const float* __restrict__ agg2, const float* __restrict__ inv_in,
                                const float* __restrict__ b2, float* __restrict__ out, int N) {
    int n = blockIdx.x * blockDim.x + threadIdx.x;
    if (n >= N) return;
    float ii = inv_in[n];
    float v[OUT_FEATS];
    float mx = -INFINITY;
    const float* ar = agg2 + (size_t)n * OUT_FEATS;
    #pragma unroll
    for (int o = 0; o < OUT_FEATS; ++o) {
        v[o] = fmaf(ar[o], ii, b2[o]);
        mx = fmaxf(mx, v[o]);
    }
    float sum = 0.0f;
    #pragma unroll
    for (int o = 0; o < OUT_FEATS; ++o) sum += __expf(v[o] - mx);
    float lse = mx + __logf(sum);
    float* orow = out + (size_t)n * OUT_FEATS;
    #pragma unroll
    for (int o = 0; o < OUT_FEATS; ++o) orow[o] = v[o] - lse;
}

extern "C" void kernel_launch(void* const* d_in, const int* in_sizes, int n_in,
                              void* d_out, int out_size, void* d_ws, size_t ws_size,
                              hipStream_t stream) {
    const float* x   = (const float*)d_in[0];
    const float* W1  = (const float*)d_in[1];
    const float* b1  = (const float*)d_in[2];
    const float* W2  = (const float*)d_in[3];
    const float* b2  = (const float*)d_in[4];
    const int*   src = (const int*)d_in[5];
    const int*   dst = (const int*)d_in[6];
    float* out = (float*)d_out;

    // -------- workspace layout (4-byte words; all offsets multiples of 4 words = 16B) --------
    char* base = (char*)d_ws;
    float* outdegF = (float*)(base);                              // [N] -> becomes inv_out
    int*   indegI  = (int*)(base + 400000L);                      // [N]
    float* inv_in  = (float*)(base + 800000L);                    // [N]
    int*   offs    = (int*)(base + 1200000L);                     // [N]
    int*   cursor  = (int*)(base + 1600000L);                     // [N]
    int*   partial = (int*)(base + 2000000L);                     // [N]
    int*   bsums   = (int*)(base + 2400000L);                     // [512]
    int*   bscan   = (int*)(base + 2402048L);                     // [512]
    int*   csr_src = (int*)(base + 2404096L);                     // [E]
    float* h       = (float*)(base + 2404096L + 12800000L);       // [N*32]
    float* agg1    = (float*)(base + 2404096L + 25600000L);       // [N*32]
    float* t2      = (float*)(base + 2404096L + 38400000L);       // [N*40]
    float* agg2    = (float*)(base + 2404096L + 54400000L);       // [N*40]
    float* inv_out = outdegF;

    const int NB_SCAN = (N_NODES + 255) / 256;  // 391

    // zero only the histogram counters (ws is poisoned 0xAA each call)
    hipMemsetAsync(outdegF, 0, 2 * 400000L, stream);  // outdegF + indegI (adjacent)

    hist_kernel<<<(N_EDGES + 255) / 256, 256, 0, stream>>>(src, dst, outdegF, indegI, N_EDGES);
    invsqrt_kernel<<<(N_NODES + 255) / 256, 256, 0, stream>>>(outdegF, indegI, inv_in, N_NODES);

    // CSR build (by dst)
    scan1_kernel<<<NB_SCAN, 256, 0, stream>>>(indegI, partial, bsums, N_NODES);
    scan2_kernel<<<1, 512, 0, stream>>>(bsums, bscan, NB_SCAN);
    scan3_kernel<<<NB_SCAN, 256, 0, stream>>>(partial, bscan, offs, cursor, N_NODES);
    fill_csr_kernel<<<(N_EDGES + 255) / 256, 256, 0, stream>>>(src, dst, cursor, csr_src, N_EDGES);

    // layer 1 dense: 4 threads per node
    gemm1_kernel<<<(N_NODES * 4 + 255) / 256, 256, 0, stream>>>(x, W1, inv_out, h, N_NODES);

    // layer 1 aggregate (gather, no atomics): 8 nodes per 256-block
    gather1_kernel<<<(N_NODES + 7) / 8, 256, 0, stream>>>(h, offs, csr_src, agg1, N_NODES);

    // relu + layer 2 dense (fused)
    fuse_gemm2_kernel<<<(N_NODES * OUT_FEATS + 255) / 256, 256, 0, stream>>>(
        agg1, inv_in, inv_out, b1, W2, t2, N_NODES);

    // layer 2 aggregate (gather): 8 nodes per 320-block
    gather2_kernel<<<(N_NODES + 7) / 8, 320, 0, stream>>>(t2, offs, csr_src, agg2, N_NODES);

    // bias + log_softmax
    finalize_kernel<<<(N_NODES + 255) / 256, 256, 0, stream>>>(agg2, inv_in, b2, out, N_NODES);
}